// Round 3
// baseline (744.983 us; speedup 1.0000x reference)
//
#include <hip/hip_runtime.h>

#define F_ 8
#define C_ 128
#define H_ 96
#define W_ 96
#define P_ (H_*W_)   // 9216
#define I_ 64
#define T_ 17
#define KK_ (F_*T_)  // 136

__constant__ int c_dy[T_] = {-1,-1,-1, 0,0,0, 1,1,1, -3,-3,-3, 0,0, 3,3,3};
__constant__ int c_dx[T_] = {-1, 0, 1,-1,0,1,-1,0,1, -3, 0, 3,-3,3,-3,0,3};

// vt[c] = sum_i wt[i]*rtw[i,c]; u[c] = sum_i wp[i]*rpw[i,c];
// ct[0] = wt.rtb; ct[1] = wp.rpb; Kc[c] = sum_i rWw[c,i]*rg_b[i]
__global__ __launch_bounds__(128) void k_prep(const float* __restrict__ rtw,
                                              const float* __restrict__ rpw,
                                              const float* __restrict__ rtb,
                                              const float* __restrict__ rpb,
                                              const float* __restrict__ cp,
                                              const float* __restrict__ rWw,
                                              const float* __restrict__ rgb_,
                                              float* __restrict__ vt,
                                              float* __restrict__ u,
                                              float* __restrict__ ct,
                                              float* __restrict__ Kc) {
    int c = threadIdx.x;  // 128
    float a = 0.f, b2 = 0.f, kk = 0.f;
    for (int i = 0; i < I_; ++i) {
        a  += cp[i]      * rtw[i*C_ + c];
        b2 += cp[I_ + i] * rpw[i*C_ + c];
        kk += rWw[c*I_ + i] * rgb_[i];
    }
    vt[c] = a; u[c] = b2; Kc[c] = kk;
    if (c == 0) { float s = 0.f; for (int i = 0; i < I_; ++i) s += cp[i]      * rtb[i]; ct[0] = s; }
    if (c == 1) { float s = 0.f; for (int i = 0; i < I_; ++i) s += cp[I_ + i] * rpb[i]; ct[1] = s; }
}

// MT[cc][c] = sum_i rWw[c,i] * rgw[i,cc]
__global__ __launch_bounds__(128) void k_mt(const float* __restrict__ rWw,
                                            const float* __restrict__ rgw,
                                            float* __restrict__ MT) {
    int cc = blockIdx.x;
    int c  = threadIdx.x;
    float s = 0.f;
    for (int i = 0; i < I_; ++i) s += rWw[c*I_ + i] * rgw[i*C_ + cc];
    MT[cc*C_ + c] = s;
}

// 4 weight transposes in one dispatch
__global__ __launch_bounds__(256) void k_tr(const float* __restrict__ g_w,
                                            const float* __restrict__ th_w,
                                            const float* __restrict__ ph_w,
                                            const float* __restrict__ W_w,
                                            float* __restrict__ gT,
                                            float* __restrict__ thT,
                                            float* __restrict__ phT,
                                            float* __restrict__ WT) {
    int which = blockIdx.y;
    int idx = blockIdx.x * 256 + threadIdx.x;
    const float* src; float* dst; int Cc;
    if      (which == 0) { src = g_w;  dst = gT;  Cc = C_; }
    else if (which == 1) { src = th_w; dst = thT; Cc = C_; }
    else if (which == 2) { src = ph_w; dst = phT; Cc = C_; }
    else                 { src = W_w;  dst = WT;  Cc = I_; }
    int R = (C_*I_) / Cc;
    int r = idx / Cc, c2 = idx % Cc;
    dst[c2 * R + r] = src[idx];
}

// three convs on x, 4px/thread via float4; folds Bf (= x . u + ct1) into proj==2,y==1
__global__ __launch_bounds__(256) void k_conv3(const float* __restrict__ x,
                                               const float* __restrict__ w0,
                                               const float* __restrict__ w1,
                                               const float* __restrict__ w2,
                                               const float* __restrict__ b0,
                                               const float* __restrict__ b1,
                                               const float* __restrict__ b2,
                                               const float* __restrict__ u,
                                               const float* __restrict__ ct,
                                               float* __restrict__ o0,
                                               float* __restrict__ o1,
                                               float* __restrict__ o2,
                                               float* __restrict__ Bf) {
    int t4 = blockIdx.x * 256 + threadIdx.x;   // float4 index, 0..P_/4-1
    int i0 = blockIdx.y * 32;
    int z  = blockIdx.z; int proj = z >> 3; int f = z & 7;
    const float* wT   = proj == 0 ? w0 : (proj == 1 ? w1 : w2);
    const float* bias = proj == 0 ? b0 : (proj == 1 ? b1 : b2);
    float*       out  = proj == 0 ? o0 : (proj == 1 ? o1 : o2);
    const float4* xp = (const float4*)(x + (size_t)f * C_ * P_) + t4;
    float4 acc[32];
#pragma unroll
    for (int ii = 0; ii < 32; ++ii) { acc[ii].x = 0.f; acc[ii].y = 0.f; acc[ii].z = 0.f; acc[ii].w = 0.f; }
    bool doBf = (proj == 2) && (blockIdx.y == 1);
    float4 accb; accb.x = accb.y = accb.z = accb.w = 0.f;
#pragma unroll 2
    for (int c = 0; c < C_; ++c) {
        float4 xv = xp[(size_t)c * (P_/4)];
        const float* wr = wT + (size_t)c * I_ + i0;   // uniform -> s_load
#pragma unroll
        for (int ii = 0; ii < 32; ++ii) {
            float w = wr[ii];
            acc[ii].x += xv.x * w; acc[ii].y += xv.y * w;
            acc[ii].z += xv.z * w; acc[ii].w += xv.w * w;
        }
        if (doBf) {
            float uv = u[c];
            accb.x += xv.x * uv; accb.y += xv.y * uv;
            accb.z += xv.z * uv; accb.w += xv.w * uv;
        }
    }
#pragma unroll
    for (int ii = 0; ii < 32; ++ii) {
        float bv = bias[i0 + ii];
        float4 r; r.x = acc[ii].x + bv; r.y = acc[ii].y + bv; r.z = acc[ii].z + bv; r.w = acc[ii].w + bv;
        ((float4*)(out + ((size_t)f * I_ + i0 + ii) * P_))[t4] = r;
    }
    if (doBf) {
        float c1 = ct[1];
        float4 r; r.x = accb.x + c1; r.y = accb.y + c1; r.z = accb.z + c1; r.w = accb.w + c1;
        ((float4*)(Bf + (size_t)f * P_))[t4] = r;
    }
}

// y<4: GRW[c][p] = Kc[c] + sum_cc MT[cc][c]*rgb[cc][p];  y==4: SR[p] = ct0 + rgb.vt
__global__ __launch_bounds__(256) void k_grw(const float* __restrict__ rgb,
                                             const float* __restrict__ MT,
                                             const float* __restrict__ Kc,
                                             const float* __restrict__ vt,
                                             const float* __restrict__ ct,
                                             float* __restrict__ GRW,
                                             float* __restrict__ SR) {
    int p = blockIdx.x * 256 + threadIdx.x;
    int y = blockIdx.y;
    if (y == 4) {
        float s = ct[0];
        for (int c = 0; c < C_; ++c) s += rgb[(size_t)c * P_ + p] * vt[c];
        SR[p] = s;
        return;
    }
    int c0 = y * 32;
    float acc[32];
#pragma unroll
    for (int ii = 0; ii < 32; ++ii) acc[ii] = 0.f;
    for (int c = 0; c < C_; ++c) {
        float xv = rgb[(size_t)c * P_ + p];
        const float* wr = MT + (size_t)c * C_ + c0;
#pragma unroll
        for (int ii = 0; ii < 32; ++ii) acc[ii] += xv * wr[ii];
    }
#pragma unroll
    for (int ii = 0; ii < 32; ++ii) GRW[(size_t)(c0 + ii) * P_ + p] = acc[ii] + Kc[c0 + ii];
}

// scores: S[f1][f2*17+t][p] = sum_i PH[f1,i,p]*TH[f2,i,q_t]; 4 f1 x 17 t x 2 px per thread
__global__ __launch_bounds__(128) void k_scores(const float* __restrict__ PH,
                                                const float* __restrict__ TH,
                                                float* __restrict__ S) {
    int pp  = (blockIdx.x * 128 + threadIdx.x) * 2;
    int f10 = blockIdx.y * 4;
    int f2  = blockIdx.z;
    int px0 = pp % W_, py0 = pp / W_;
    int px1 = px0 + 1, py1 = py0;
    if (px1 == W_) { px1 = 0; ++py1; }
    int   q0[T_], q1[T_];
    float m0[T_], m1[T_];
#pragma unroll
    for (int t = 0; t < T_; ++t) {
        int dy = c_dy[t], dx = c_dx[t];
        bool v0 = ((unsigned)(py0 + dy) < H_) && ((unsigned)(px0 + dx) < W_);
        bool v1 = ((unsigned)(py1 + dy) < H_) && ((unsigned)(px1 + dx) < W_);
        int a0 = pp     + dy * W_ + dx; a0 = min(max(a0, 0), P_ - 1);
        int a1 = pp + 1 + dy * W_ + dx; a1 = min(max(a1, 0), P_ - 1);
        q0[t] = a0; q1[t] = a1;
        m0[t] = v0 ? 1.f : 0.f; m1[t] = v1 ? 1.f : 0.f;
    }
    const float* THb = TH + (size_t)f2 * I_ * P_;
    float acc[4][T_][2];
#pragma unroll
    for (int ff = 0; ff < 4; ++ff)
#pragma unroll
        for (int t = 0; t < T_; ++t) { acc[ff][t][0] = 0.f; acc[ff][t][1] = 0.f; }
    for (int i = 0; i < I_; ++i) {
        float2 ph[4];
#pragma unroll
        for (int ff = 0; ff < 4; ++ff)
            ph[ff] = ((const float2*)(PH + ((size_t)(f10 + ff) * I_ + i) * P_))[pp >> 1];
        const float* tr = THb + (size_t)i * P_;
#pragma unroll
        for (int t = 0; t < T_; ++t) {
            float tv0 = tr[q0[t]], tv1 = tr[q1[t]];
#pragma unroll
            for (int ff = 0; ff < 4; ++ff) {
                acc[ff][t][0] += ph[ff].x * tv0;
                acc[ff][t][1] += ph[ff].y * tv1;
            }
        }
    }
#pragma unroll
    for (int ff = 0; ff < 4; ++ff)
#pragma unroll
        for (int t = 0; t < T_; ++t) {
            float2 r; r.x = acc[ff][t][0] * m0[t]; r.y = acc[ff][t][1] * m1[t];
            ((float2*)(S + ((size_t)(f10 + ff) * KK_ + f2 * T_ + t) * P_))[pp >> 1] = r;
        }
}

__global__ __launch_bounds__(128) void k_softmax(float* __restrict__ S,
                                                 float* __restrict__ den) {
    int pp = (blockIdx.x * 128 + threadIdx.x) * 2;
    int f1 = blockIdx.y;
    float* sp = S + (size_t)f1 * KK_ * P_ + pp;
    float mx = -1e30f, my = -1e30f;
    for (int k = 0; k < KK_; ++k) {
        float2 v = *(const float2*)(sp + (size_t)k * P_);
        mx = fmaxf(mx, v.x); my = fmaxf(my, v.y);
    }
    float sx = 0.f, sy = 0.f;
    for (int k = 0; k < KK_; ++k) {
        float2 v = *(const float2*)(sp + (size_t)k * P_);
        float2 e; e.x = __expf(v.x - mx); e.y = __expf(v.y - my);
        *(float2*)(sp + (size_t)k * P_) = e;
        sx += e.x; sy += e.y;
    }
    float2 d; d.x = 1.f / sx; d.y = 1.f / sy;
    ((float2*)(den + f1 * P_))[pp >> 1] = d;
}

// Y[f1][i][p] = (sum_{f2,t} Sexp*m * G[f2][i][q_t]) * den; 2 f1 x 16 i x 2 px
__global__ __launch_bounds__(128) void k_y(const float* __restrict__ S,
                                           const float* __restrict__ G,
                                           const float* __restrict__ den,
                                           float* __restrict__ Y) {
    int pp  = (blockIdx.x * 128 + threadIdx.x) * 2;
    int f10 = blockIdx.y * 2;
    int i0  = blockIdx.z * 16;
    int px0 = pp % W_, py0 = pp / W_;
    int px1 = px0 + 1, py1 = py0;
    if (px1 == W_) { px1 = 0; ++py1; }
    int   q0[T_], q1[T_];
    float m0[T_], m1[T_];
#pragma unroll
    for (int t = 0; t < T_; ++t) {
        int dy = c_dy[t], dx = c_dx[t];
        bool v0 = ((unsigned)(py0 + dy) < H_) && ((unsigned)(px0 + dx) < W_);
        bool v1 = ((unsigned)(py1 + dy) < H_) && ((unsigned)(px1 + dx) < W_);
        int a0 = pp     + dy * W_ + dx; a0 = min(max(a0, 0), P_ - 1);
        int a1 = pp + 1 + dy * W_ + dx; a1 = min(max(a1, 0), P_ - 1);
        q0[t] = a0; q1[t] = a1;
        m0[t] = v0 ? 1.f : 0.f; m1[t] = v1 ? 1.f : 0.f;
    }
    float acc[2][16][2];
#pragma unroll
    for (int ff = 0; ff < 2; ++ff)
#pragma unroll
        for (int ii = 0; ii < 16; ++ii) { acc[ff][ii][0] = 0.f; acc[ff][ii][1] = 0.f; }
    for (int f2 = 0; f2 < F_; ++f2) {
        const float* Gb = G + ((size_t)f2 * I_ + i0) * P_;
#pragma unroll
        for (int t = 0; t < T_; ++t) {
            float s0[2], s1[2];
#pragma unroll
            for (int ff = 0; ff < 2; ++ff) {
                float2 sv = ((const float2*)(S + ((size_t)(f10 + ff) * KK_ + f2 * T_ + t) * P_))[pp >> 1];
                s0[ff] = sv.x * m0[t]; s1[ff] = sv.y * m1[t];
            }
#pragma unroll
            for (int ii = 0; ii < 16; ++ii) {
                const float* gr = Gb + (size_t)ii * P_;
                float g0 = gr[q0[t]], g1 = gr[q1[t]];
#pragma unroll
                for (int ff = 0; ff < 2; ++ff) {
                    acc[ff][ii][0] += s0[ff] * g0;
                    acc[ff][ii][1] += s1[ff] * g1;
                }
            }
        }
    }
#pragma unroll
    for (int ff = 0; ff < 2; ++ff) {
        float2 dv = ((const float2*)(den + (f10 + ff) * P_))[pp >> 1];
#pragma unroll
        for (int ii = 0; ii < 16; ++ii) {
            float2 r; r.x = acc[ff][ii][0] * dv.x; r.y = acc[ff][ii][1] * dv.y;
            ((float2*)(Y + ((size_t)(f10 + ff) * I_ + i0 + ii) * P_))[pp >> 1] = r;
        }
    }
}

// out[f][c][p] = Y-conv + GRW tap-sum + biases + residual; 16 c per thread, x prefetched
__global__ __launch_bounds__(256) void k_final(const float* __restrict__ Y,
                                               const float* __restrict__ WT,
                                               const float* __restrict__ Wb,
                                               const float* __restrict__ rWb,
                                               const float* __restrict__ SR,
                                               const float* __restrict__ Bf,
                                               const float* __restrict__ GRW,
                                               const float* __restrict__ x,
                                               float* __restrict__ out) {
    int p  = blockIdx.x * 256 + threadIdx.x;
    int f  = blockIdx.y;
    int c0 = blockIdx.z * 16;
    // prefetch x residual (HBM) first; consumed last
    float xres[16];
#pragma unroll
    for (int cc = 0; cc < 16; ++cc)
        xres[cc] = x[((size_t)f * C_ + c0 + cc) * P_ + p];
    int px = p % W_, py = p / W_;
    float bv = Bf[f * P_ + p];
    float fr[T_]; int qs[T_];
#pragma unroll
    for (int t = 0; t < T_; ++t) {
        int dy = c_dy[t], dx = c_dx[t];
        bool v = ((unsigned)(py + dy) < H_) && ((unsigned)(px + dx) < W_);
        int q  = p + dy * W_ + dx;
        q = min(max(q, 0), P_ - 1);
        qs[t] = q;
        fr[t] = v ? fmaxf(SR[q] + bv, 0.f) * (1.f / (float)T_) : 0.f;
    }
    float acc[16];
#pragma unroll
    for (int cc = 0; cc < 16; ++cc) acc[cc] = 0.f;
    const float* yp = Y + (size_t)f * I_ * P_ + p;
#pragma unroll 4
    for (int i = 0; i < I_; ++i) {
        float yv = yp[(size_t)i * P_];
        const float* wr = WT + (size_t)i * C_ + c0;   // uniform -> s_load
#pragma unroll
        for (int cc = 0; cc < 16; ++cc) acc[cc] += yv * wr[cc];
    }
#pragma unroll 2
    for (int t = 0; t < T_; ++t) {
        float fv = fr[t];
        const float* gp = GRW + qs[t];
#pragma unroll
        for (int cc = 0; cc < 16; ++cc)
            acc[cc] += fv * gp[(size_t)(c0 + cc) * P_];
    }
#pragma unroll
    for (int cc = 0; cc < 16; ++cc) {
        size_t o = ((size_t)f * C_ + c0 + cc) * P_ + p;
        out[o] = acc[cc] + xres[cc] + Wb[c0 + cc] + rWb[c0 + cc];
    }
}

extern "C" void kernel_launch(void* const* d_in, const int* in_sizes, int n_in,
                              void* d_out, int out_size, void* d_ws, size_t ws_size,
                              hipStream_t stream) {
    const float* x    = (const float*)d_in[0];
    const float* rgb  = (const float*)d_in[1];
    const float* g_w  = (const float*)d_in[2];
    const float* g_b  = (const float*)d_in[3];
    const float* th_w = (const float*)d_in[4];
    const float* th_b = (const float*)d_in[5];
    const float* ph_w = (const float*)d_in[6];
    const float* ph_b = (const float*)d_in[7];
    const float* W_w  = (const float*)d_in[8];
    const float* W_b  = (const float*)d_in[9];
    const float* rg_w = (const float*)d_in[10];
    const float* rg_b = (const float*)d_in[11];
    const float* rt_w = (const float*)d_in[12];
    const float* rt_b = (const float*)d_in[13];
    const float* rp_w = (const float*)d_in[14];
    const float* rp_b = (const float*)d_in[15];
    const float* rW_w = (const float*)d_in[16];
    const float* rW_b = (const float*)d_in[17];
    const float* cp_w = (const float*)d_in[18];
    float* out = (float*)d_out;

    const size_t FIP = (size_t)F_ * I_ * P_;   // 4718592
    const size_t SKP = (size_t)F_ * KK_ * P_;  // 10027008

    float* ws  = (float*)d_ws;
    float* G   = ws;
    float* TH  = G + FIP;
    float* PH  = TH + FIP;
    float* S   = PH + FIP;
    float* DEN = S + SKP;
    float* SR  = DEN + (size_t)F_ * P_;
    float* Bf  = SR + P_;
    float* VT  = Bf + (size_t)F_ * P_;
    float* U   = VT + C_;
    float* CT  = U + C_;
    float* Kc  = CT + 2;
    float* MT  = Kc + C_;
    float* gT  = MT + (size_t)C_ * C_;
    float* thT = gT + (size_t)C_ * I_;
    float* phT = thT + (size_t)C_ * I_;
    float* WT  = phT + (size_t)C_ * I_;
    float* Y   = TH;   // alias: TH dead after k_scores
    float* GRW = PH;   // alias: PH dead after k_scores (k_grw runs after k_scores)

    // weight prep
    k_prep<<<1, 128, 0, stream>>>(rt_w, rp_w, rt_b, rp_b, cp_w, rW_w, rg_b, VT, U, CT, Kc);
    k_mt<<<128, 128, 0, stream>>>(rW_w, rg_w, MT);
    k_tr<<<dim3(32, 4), 256, 0, stream>>>(g_w, th_w, ph_w, W_w, gT, thT, phT, WT);

    // projections of x (G, TH, PH) + Bf fold
    k_conv3<<<dim3(P_ / 1024, 2, 24), 256, 0, stream>>>(x, gT, thT, phT,
                                                        g_b, th_b, ph_b, U, CT,
                                                        G, TH, PH, Bf);

    // attention scores
    k_scores<<<dim3(P_ / 256, 2, F_), 128, 0, stream>>>(PH, TH, S);

    // GRW + SR (PH region reuse after k_scores)
    k_grw<<<dim3(P_ / 256, 5), 256, 0, stream>>>(rgb, MT, Kc, VT, CT, GRW, SR);

    k_softmax<<<dim3(P_ / 256, F_), 128, 0, stream>>>(S, DEN);

    // attention apply
    k_y<<<dim3(P_ / 256, F_ / 2, I_ / 16), 128, 0, stream>>>(S, G, DEN, Y);

    // final: W*Y + rgb-branch taps + biases + residual
    k_final<<<dim3(P_ / 256, F_, C_ / 16), 256, 0, stream>>>(Y, WT, W_b, rW_b,
                                                             SR, Bf, GRW, x, out);
}

// Round 4
// 311.543 us; speedup vs baseline: 2.3913x; 2.3913x over previous
//
#include <hip/hip_runtime.h>

#define F_ 8
#define C_ 128
#define H_ 96
#define W_ 96
#define P_ (H_*W_)   // 9216
#define I_ 64
#define T_ 17
#define KK_ (F_*T_)  // 136

__constant__ int c_dy[T_] = {-1,-1,-1, 0,0,0, 1,1,1, -3,-3,-3, 0,0, 3,3,3};
__constant__ int c_dx[T_] = {-1, 0, 1,-1,0,1,-1,0,1, -3, 0, 3,-3,3,-3,0,3};

// vt[c] = sum_i wt[i]*rtw[i,c]; u[c] = sum_i wp[i]*rpw[i,c];
// ct[0] = wt.rtb; ct[1] = wp.rpb; Kc[c] = sum_i rWw[c,i]*rg_b[i]
__global__ __launch_bounds__(128) void k_prep(const float* __restrict__ rtw,
                                              const float* __restrict__ rpw,
                                              const float* __restrict__ rtb,
                                              const float* __restrict__ rpb,
                                              const float* __restrict__ cp,
                                              const float* __restrict__ rWw,
                                              const float* __restrict__ rgb_,
                                              float* __restrict__ vt,
                                              float* __restrict__ u,
                                              float* __restrict__ ct,
                                              float* __restrict__ Kc) {
    int c = threadIdx.x;  // 128
    float a = 0.f, b2 = 0.f, kk = 0.f;
    for (int i = 0; i < I_; ++i) {
        a  += cp[i]      * rtw[i*C_ + c];
        b2 += cp[I_ + i] * rpw[i*C_ + c];
        kk += rWw[c*I_ + i] * rgb_[i];
    }
    vt[c] = a; u[c] = b2; Kc[c] = kk;
    if (c == 0) { float s = 0.f; for (int i = 0; i < I_; ++i) s += cp[i]      * rtb[i]; ct[0] = s; }
    if (c == 1) { float s = 0.f; for (int i = 0; i < I_; ++i) s += cp[I_ + i] * rpb[i]; ct[1] = s; }
}

// MT[cc][c] = sum_i rWw[c,i] * rgw[i,cc]
__global__ __launch_bounds__(128) void k_mt(const float* __restrict__ rWw,
                                            const float* __restrict__ rgw,
                                            float* __restrict__ MT) {
    int cc = blockIdx.x;
    int c  = threadIdx.x;
    float s = 0.f;
    for (int i = 0; i < I_; ++i) s += rWw[c*I_ + i] * rgw[i*C_ + cc];
    MT[cc*C_ + c] = s;
}

// 4 weight transposes in one dispatch
__global__ __launch_bounds__(256) void k_tr(const float* __restrict__ g_w,
                                            const float* __restrict__ th_w,
                                            const float* __restrict__ ph_w,
                                            const float* __restrict__ W_w,
                                            float* __restrict__ gT,
                                            float* __restrict__ thT,
                                            float* __restrict__ phT,
                                            float* __restrict__ WT) {
    int which = blockIdx.y;
    int idx = blockIdx.x * 256 + threadIdx.x;
    const float* src; float* dst; int Cc;
    if      (which == 0) { src = g_w;  dst = gT;  Cc = C_; }
    else if (which == 1) { src = th_w; dst = thT; Cc = C_; }
    else if (which == 2) { src = ph_w; dst = phT; Cc = C_; }
    else                 { src = W_w;  dst = WT;  Cc = I_; }
    int R = (C_*I_) / Cc;
    int r = idx / Cc, c2 = idx % Cc;
    dst[c2 * R + r] = src[idx];
}

// three convs on x, 4px/thread via float4; folds Bf (= x . u + ct1) into proj==2,y==1
__global__ __launch_bounds__(256) void k_conv3(const float* __restrict__ x,
                                               const float* __restrict__ w0,
                                               const float* __restrict__ w1,
                                               const float* __restrict__ w2,
                                               const float* __restrict__ b0,
                                               const float* __restrict__ b1,
                                               const float* __restrict__ b2,
                                               const float* __restrict__ u,
                                               const float* __restrict__ ct,
                                               float* __restrict__ o0,
                                               float* __restrict__ o1,
                                               float* __restrict__ o2,
                                               float* __restrict__ Bf) {
    int t4 = blockIdx.x * 256 + threadIdx.x;   // float4 index, 0..P_/4-1
    int i0 = blockIdx.y * 32;
    int z  = blockIdx.z; int proj = z >> 3; int f = z & 7;
    const float* wT   = proj == 0 ? w0 : (proj == 1 ? w1 : w2);
    const float* bias = proj == 0 ? b0 : (proj == 1 ? b1 : b2);
    float*       out  = proj == 0 ? o0 : (proj == 1 ? o1 : o2);
    const float4* xp = (const float4*)(x + (size_t)f * C_ * P_) + t4;
    float4 acc[32];
#pragma unroll
    for (int ii = 0; ii < 32; ++ii) { acc[ii].x = 0.f; acc[ii].y = 0.f; acc[ii].z = 0.f; acc[ii].w = 0.f; }
    bool doBf = (proj == 2) && (blockIdx.y == 1);
    float4 accb; accb.x = accb.y = accb.z = accb.w = 0.f;
#pragma unroll 2
    for (int c = 0; c < C_; ++c) {
        float4 xv = xp[(size_t)c * (P_/4)];
        const float* wr = wT + (size_t)c * I_ + i0;   // uniform -> s_load
#pragma unroll
        for (int ii = 0; ii < 32; ++ii) {
            float w = wr[ii];
            acc[ii].x += xv.x * w; acc[ii].y += xv.y * w;
            acc[ii].z += xv.z * w; acc[ii].w += xv.w * w;
        }
        if (doBf) {
            float uv = u[c];
            accb.x += xv.x * uv; accb.y += xv.y * uv;
            accb.z += xv.z * uv; accb.w += xv.w * uv;
        }
    }
#pragma unroll
    for (int ii = 0; ii < 32; ++ii) {
        float bv = bias[i0 + ii];
        float4 r; r.x = acc[ii].x + bv; r.y = acc[ii].y + bv; r.z = acc[ii].z + bv; r.w = acc[ii].w + bv;
        ((float4*)(out + ((size_t)f * I_ + i0 + ii) * P_))[t4] = r;
    }
    if (doBf) {
        float c1 = ct[1];
        float4 r; r.x = accb.x + c1; r.y = accb.y + c1; r.z = accb.z + c1; r.w = accb.w + c1;
        ((float4*)(Bf + (size_t)f * P_))[t4] = r;
    }
}

// y<4: GRW[c][p] = Kc[c] + sum_cc MT[cc][c]*rgb[cc][p];  y==4: SR[p] = ct0 + rgb.vt
__global__ __launch_bounds__(256) void k_grw(const float* __restrict__ rgb,
                                             const float* __restrict__ MT,
                                             const float* __restrict__ Kc,
                                             const float* __restrict__ vt,
                                             const float* __restrict__ ct,
                                             float* __restrict__ GRW,
                                             float* __restrict__ SR) {
    int p = blockIdx.x * 256 + threadIdx.x;
    int y = blockIdx.y;
    if (y == 4) {
        float s = ct[0];
        for (int c = 0; c < C_; ++c) s += rgb[(size_t)c * P_ + p] * vt[c];
        SR[p] = s;
        return;
    }
    int c0 = y * 32;
    float acc[32];
#pragma unroll
    for (int ii = 0; ii < 32; ++ii) acc[ii] = 0.f;
    for (int c = 0; c < C_; ++c) {
        float xv = rgb[(size_t)c * P_ + p];
        const float* wr = MT + (size_t)c * C_ + c0;
#pragma unroll
        for (int ii = 0; ii < 32; ++ii) acc[ii] += xv * wr[ii];
    }
#pragma unroll
    for (int ii = 0; ii < 32; ++ii) GRW[(size_t)(c0 + ii) * P_ + p] = acc[ii] + Kc[c0 + ii];
}

// scores: S[f1][k][p] = sum_i PH[f1,i,p]*TH[f2(k),i,q_k]; thread = 1px x 8f1 x 8k
__global__ __launch_bounds__(256) void k_scores(const float* __restrict__ PH,
                                                const float* __restrict__ TH,
                                                float* __restrict__ S) {
    int p  = blockIdx.x * 256 + threadIdx.x;
    int k0 = blockIdx.y * 8;
    int px = p % W_, py = p / W_;
    size_t tb[8]; float msk[8];
#pragma unroll
    for (int kk = 0; kk < 8; ++kk) {
        int k  = k0 + kk;
        int f2 = k / T_;
        int t  = k - f2 * T_;
        int dy = c_dy[t], dx = c_dx[t];
        bool v = ((unsigned)(py + dy) < H_) && ((unsigned)(px + dx) < W_);
        int q  = p + dy * W_ + dx;
        q = min(max(q, 0), P_ - 1);
        tb[kk]  = (size_t)f2 * I_ * P_ + q;
        msk[kk] = v ? 1.f : 0.f;
    }
    float acc[8][8];
#pragma unroll
    for (int a = 0; a < 8; ++a)
#pragma unroll
        for (int b = 0; b < 8; ++b) acc[a][b] = 0.f;
    for (int i = 0; i < I_; ++i) {
        float phv[8];
#pragma unroll
        for (int f1 = 0; f1 < 8; ++f1) phv[f1] = PH[((size_t)f1 * I_ + i) * P_ + p];
#pragma unroll
        for (int kk = 0; kk < 8; ++kk) {
            float tv = TH[tb[kk] + (size_t)i * P_];
#pragma unroll
            for (int f1 = 0; f1 < 8; ++f1) acc[f1][kk] += phv[f1] * tv;
        }
    }
#pragma unroll
    for (int f1 = 0; f1 < 8; ++f1)
#pragma unroll
        for (int kk = 0; kk < 8; ++kk)
            S[((size_t)f1 * KK_ + k0 + kk) * P_ + p] = acc[f1][kk] * msk[kk];
}

__global__ __launch_bounds__(128) void k_softmax(float* __restrict__ S,
                                                 float* __restrict__ den) {
    int pp = (blockIdx.x * 128 + threadIdx.x) * 2;
    int f1 = blockIdx.y;
    float* sp = S + (size_t)f1 * KK_ * P_ + pp;
    float mx = -1e30f, my = -1e30f;
    for (int k = 0; k < KK_; ++k) {
        float2 v = *(const float2*)(sp + (size_t)k * P_);
        mx = fmaxf(mx, v.x); my = fmaxf(my, v.y);
    }
    float sx = 0.f, sy = 0.f;
    for (int k = 0; k < KK_; ++k) {
        float2 v = *(const float2*)(sp + (size_t)k * P_);
        float2 e; e.x = __expf(v.x - mx); e.y = __expf(v.y - my);
        *(float2*)(sp + (size_t)k * P_) = e;
        sx += e.x; sy += e.y;
    }
    float2 d; d.x = 1.f / sx; d.y = 1.f / sy;
    ((float2*)(den + f1 * P_))[pp >> 1] = d;
}

// Y[f1][i][p] = (sum_{f2,t} Sexp[f1][f2t][p]*m_t * G[f2][i][q_t]) * den[f1][p]
// thread = 1 px x ALL 8 f1 x 8 i  (G traffic shared across all f1: 321MB total)
__global__ __launch_bounds__(128) void k_y(const float* __restrict__ S,
                                           const float* __restrict__ G,
                                           const float* __restrict__ den,
                                           float* __restrict__ Y) {
    int p  = blockIdx.x * 128 + threadIdx.x;
    int i0 = blockIdx.y * 8;
    int px = p % W_, py = p / W_;
    int qs[T_]; float ms[T_];
#pragma unroll
    for (int t = 0; t < T_; ++t) {
        int dy = c_dy[t], dx = c_dx[t];
        bool v = ((unsigned)(py + dy) < H_) && ((unsigned)(px + dx) < W_);
        int q  = p + dy * W_ + dx;
        q = min(max(q, 0), P_ - 1);
        qs[t] = q;
        ms[t] = v ? 1.f : 0.f;
    }
    float acc[8][8];
#pragma unroll
    for (int a = 0; a < 8; ++a)
#pragma unroll
        for (int b = 0; b < 8; ++b) acc[a][b] = 0.f;
#pragma unroll 1
    for (int f2 = 0; f2 < F_; ++f2) {
        const float* Gb = G + ((size_t)f2 * I_ + i0) * P_;
        const float* Sb = S + (size_t)f2 * T_ * P_ + p;
#pragma unroll 1
        for (int t = 0; t < T_; ++t) {
            // 16 independent loads per step, then 64 FMA
            float sv[8];
#pragma unroll
            for (int ff = 0; ff < 8; ++ff)
                sv[ff] = Sb[((size_t)ff * KK_ + t) * P_];
            float gv[8];
            const float* gq = Gb + qs[t];
#pragma unroll
            for (int ii = 0; ii < 8; ++ii)
                gv[ii] = gq[(size_t)ii * P_];
            float mt = ms[t];
#pragma unroll
            for (int ii = 0; ii < 8; ++ii) gv[ii] *= mt;
#pragma unroll
            for (int ff = 0; ff < 8; ++ff)
#pragma unroll
                for (int ii = 0; ii < 8; ++ii)
                    acc[ff][ii] += sv[ff] * gv[ii];
        }
    }
#pragma unroll
    for (int ff = 0; ff < 8; ++ff) {
        float dv = den[ff * P_ + p];
#pragma unroll
        for (int ii = 0; ii < 8; ++ii)
            Y[((size_t)ff * I_ + i0 + ii) * P_ + p] = acc[ff][ii] * dv;
    }
}

// out[f][c][p] = Y-conv + GRW tap-sum + biases + residual; 16 c per thread, x prefetched
__global__ __launch_bounds__(256) void k_final(const float* __restrict__ Y,
                                               const float* __restrict__ WT,
                                               const float* __restrict__ Wb,
                                               const float* __restrict__ rWb,
                                               const float* __restrict__ SR,
                                               const float* __restrict__ Bf,
                                               const float* __restrict__ GRW,
                                               const float* __restrict__ x,
                                               float* __restrict__ out) {
    int p  = blockIdx.x * 256 + threadIdx.x;
    int f  = blockIdx.y;
    int c0 = blockIdx.z * 16;
    // prefetch x residual (HBM) first; consumed last
    float xres[16];
#pragma unroll
    for (int cc = 0; cc < 16; ++cc)
        xres[cc] = x[((size_t)f * C_ + c0 + cc) * P_ + p];
    int px = p % W_, py = p / W_;
    float bv = Bf[f * P_ + p];
    float fr[T_]; int qs[T_];
#pragma unroll
    for (int t = 0; t < T_; ++t) {
        int dy = c_dy[t], dx = c_dx[t];
        bool v = ((unsigned)(py + dy) < H_) && ((unsigned)(px + dx) < W_);
        int q  = p + dy * W_ + dx;
        q = min(max(q, 0), P_ - 1);
        qs[t] = q;
        fr[t] = v ? fmaxf(SR[q] + bv, 0.f) * (1.f / (float)T_) : 0.f;
    }
    float acc[16];
#pragma unroll
    for (int cc = 0; cc < 16; ++cc) acc[cc] = 0.f;
    const float* yp = Y + (size_t)f * I_ * P_ + p;
#pragma unroll 4
    for (int i = 0; i < I_; ++i) {
        float yv = yp[(size_t)i * P_];
        const float* wr = WT + (size_t)i * C_ + c0;   // uniform -> s_load
#pragma unroll
        for (int cc = 0; cc < 16; ++cc) acc[cc] += yv * wr[cc];
    }
#pragma unroll 2
    for (int t = 0; t < T_; ++t) {
        float fv = fr[t];
        const float* gp = GRW + qs[t];
#pragma unroll
        for (int cc = 0; cc < 16; ++cc)
            acc[cc] += fv * gp[(size_t)(c0 + cc) * P_];
    }
#pragma unroll
    for (int cc = 0; cc < 16; ++cc) {
        size_t o = ((size_t)f * C_ + c0 + cc) * P_ + p;
        out[o] = acc[cc] + xres[cc] + Wb[c0 + cc] + rWb[c0 + cc];
    }
}

extern "C" void kernel_launch(void* const* d_in, const int* in_sizes, int n_in,
                              void* d_out, int out_size, void* d_ws, size_t ws_size,
                              hipStream_t stream) {
    const float* x    = (const float*)d_in[0];
    const float* rgb  = (const float*)d_in[1];
    const float* g_w  = (const float*)d_in[2];
    const float* g_b  = (const float*)d_in[3];
    const float* th_w = (const float*)d_in[4];
    const float* th_b = (const float*)d_in[5];
    const float* ph_w = (const float*)d_in[6];
    const float* ph_b = (const float*)d_in[7];
    const float* W_w  = (const float*)d_in[8];
    const float* W_b  = (const float*)d_in[9];
    const float* rg_w = (const float*)d_in[10];
    const float* rg_b = (const float*)d_in[11];
    const float* rt_w = (const float*)d_in[12];
    const float* rt_b = (const float*)d_in[13];
    const float* rp_w = (const float*)d_in[14];
    const float* rp_b = (const float*)d_in[15];
    const float* rW_w = (const float*)d_in[16];
    const float* rW_b = (const float*)d_in[17];
    const float* cp_w = (const float*)d_in[18];
    float* out = (float*)d_out;

    const size_t FIP = (size_t)F_ * I_ * P_;   // 4718592
    const size_t SKP = (size_t)F_ * KK_ * P_;  // 10027008

    float* ws  = (float*)d_ws;
    float* G   = ws;
    float* TH  = G + FIP;
    float* PH  = TH + FIP;
    float* S   = PH + FIP;
    float* DEN = S + SKP;
    float* SR  = DEN + (size_t)F_ * P_;
    float* Bf  = SR + P_;
    float* VT  = Bf + (size_t)F_ * P_;
    float* U   = VT + C_;
    float* CT  = U + C_;
    float* Kc  = CT + 2;
    float* MT  = Kc + C_;
    float* gT  = MT + (size_t)C_ * C_;
    float* thT = gT + (size_t)C_ * I_;
    float* phT = thT + (size_t)C_ * I_;
    float* WT  = phT + (size_t)C_ * I_;
    float* Y   = TH;   // alias: TH dead after k_scores
    float* GRW = PH;   // alias: PH dead after k_scores (k_grw runs after k_scores)

    // weight prep
    k_prep<<<1, 128, 0, stream>>>(rt_w, rp_w, rt_b, rp_b, cp_w, rW_w, rg_b, VT, U, CT, Kc);
    k_mt<<<128, 128, 0, stream>>>(rW_w, rg_w, MT);
    k_tr<<<dim3(32, 4), 256, 0, stream>>>(g_w, th_w, ph_w, W_w, gT, thT, phT, WT);

    // projections of x (G, TH, PH) + Bf fold
    k_conv3<<<dim3(P_ / 1024, 2, 24), 256, 0, stream>>>(x, gT, thT, phT,
                                                        g_b, th_b, ph_b, U, CT,
                                                        G, TH, PH, Bf);

    // attention scores
    k_scores<<<dim3(P_ / 256, KK_ / 8), 256, 0, stream>>>(PH, TH, S);

    // GRW + SR (PH region reuse after k_scores)
    k_grw<<<dim3(P_ / 256, 5), 256, 0, stream>>>(rgb, MT, Kc, VT, CT, GRW, SR);

    k_softmax<<<dim3(P_ / 256, F_), 128, 0, stream>>>(S, DEN);

    // attention apply: 1px x 8f1 x 8i per thread
    k_y<<<dim3(P_ / 128, I_ / 8), 128, 0, stream>>>(S, G, DEN, Y);

    // final: W*Y + rgb-branch taps + biases + residual
    k_final<<<dim3(P_ / 256, F_, C_ / 16), 256, 0, stream>>>(Y, WT, W_b, rW_b,
                                                             SR, Bf, GRW, x, out);
}